// Round 15
// baseline (172.055 us; speedup 1.0000x reference)
//
#include <hip/hip_runtime.h>
#include <stdint.h>
#include <stddef.h>

typedef __bf16 bf16;
typedef __bf16 bf16x4 __attribute__((ext_vector_type(4)));
typedef __bf16 bf16x8 __attribute__((ext_vector_type(8)));
typedef float  f32x4  __attribute__((ext_vector_type(4)));
typedef float  f32x16 __attribute__((ext_vector_type(16)));
typedef float  f32x4v __attribute__((ext_vector_type(4)));

// async global->LDS, 16B per lane, wave-uniform LDS base + lane*16
__device__ __forceinline__ void gload_lds16(const void* g, void* lds) {
  __builtin_amdgcn_global_load_lds(
      (__attribute__((address_space(1))) void*)(uintptr_t)g,
      (__attribute__((address_space(3))) void*)lds,
      16, 0, 0);
}

// ---------------- conversion kernels ----------------

__global__ void cvt_f32_to_bf16(const float* __restrict__ in, bf16* __restrict__ out, int n) {
  int i = (blockIdx.x * blockDim.x + threadIdx.x) * 4;
  if (i >= n) return;
  f32x4v v = *reinterpret_cast<const f32x4v*>(in + i);
  bf16x4 o;
  o[0] = (bf16)v[0]; o[1] = (bf16)v[1]; o[2] = (bf16)v[2]; o[3] = (bf16)v[3];
  *reinterpret_cast<bf16x4*>(out + i) = o;
}

// in [R][C] f32  ->  out [C][R] bf16   (R,C multiples of 32)
__global__ void transpose_cvt(const float* __restrict__ in, bf16* __restrict__ out, int R, int C) {
  __shared__ bf16 tile[32][33];
  int c0 = blockIdx.x * 32, r0 = blockIdx.y * 32;
  int tx = threadIdx.x, ty = threadIdx.y;
  #pragma unroll
  for (int i = ty; i < 32; i += 8)
    tile[i][tx] = (bf16)in[(size_t)(r0 + i) * C + (c0 + tx)];
  __syncthreads();
  #pragma unroll
  for (int i = ty; i < 32; i += 8)
    out[(size_t)(c0 + i) * R + (r0 + tx)] = tile[tx][i];
}

// ---------------- GEMM: C[M][N] = A[M][K] * Bt[N][K]^T (+bias) ----------------
// 128x128 tile, BK=64, 4 waves in 2x2, each wave 64x64 (4x4 16x16 fragments).
// Proven 2-barrier structure (67.2us GEMM1 / 786 TF, conflicts 0). Both
// 8-phase/256^2 ports (R9 drain-0, R14 counted-vmcnt) regressed to ~75us:
// 128KB LDS -> 1 block/CU -> per-phase barriers stall the whole CU.
// Structural schedule attempts closed; this is the keeper. XCD-chunked
// swizzle kept (neutral-to-positive, bijective since grid%8==0).

template <typename OT, bool BIAS>
__global__ __launch_bounds__(256) void gemm_abt(
    const bf16* __restrict__ A,   // [M][K]
    const bf16* __restrict__ Bt,  // [N][K]
    const float* __restrict__ bias,
    OT* __restrict__ C, int M, int N, int K)
{
  __shared__ bf16 As[128 * 64];
  __shared__ bf16 Bs[128 * 64];

  const int tid = threadIdx.x;
  const int w = tid >> 6, l = tid & 63;
  const int l15 = l & 15, l4 = l >> 4, l7 = l & 7;
  const int wr = w >> 1, wc = w & 1;

  const int nwgx = N >> 7;
  const int nwg  = (M >> 7) * nwgx;
  const int cpx  = nwg >> 3;
  const int bid  = blockIdx.x;
  const int swz  = (bid & 7) * cpx + (bid >> 3);
  const int m0 = (swz / nwgx) * 128, n0 = (swz % nwgx) * 128;

  f32x4 acc[4][4];
  #pragma unroll
  for (int i = 0; i < 4; i++)
    #pragma unroll
    for (int j = 0; j < 4; j++) acc[i][j] = (f32x4){0.f, 0.f, 0.f, 0.f};

  const int srow  = w * 8 + (l >> 3);
  const int sslot = (l & 7) ^ ((l >> 3) & 7);
  const int KT = K >> 6;

  for (int kt = 0; kt < KT; ++kt) {
    __syncthreads();
    const int kcol = kt * 64 + sslot * 8;
    #pragma unroll
    for (int p = 0; p < 4; ++p) {
      gload_lds16(A  + (size_t)(m0 + p * 32 + srow) * K + kcol,
                  (char*)As + p * 4096 + w * 1024);
      gload_lds16(Bt + (size_t)(n0 + p * 32 + srow) * K + kcol,
                  (char*)Bs + p * 4096 + w * 1024);
    }
    __syncthreads();

    #pragma unroll
    for (int kk = 0; kk < 2; ++kk) {
      const int coff = (kk * 32 + l4 * 8) ^ (l7 << 3);
      bf16x8 af[4], bq[4];
      #pragma unroll
      for (int m = 0; m < 4; ++m) {
        int r = wr * 64 + m * 16 + l15;
        af[m] = *reinterpret_cast<const bf16x8*>(&As[r * 64 + coff]);
      }
      #pragma unroll
      for (int n = 0; n < 4; ++n) {
        int r = wc * 64 + n * 16 + l15;
        bq[n] = *reinterpret_cast<const bf16x8*>(&Bs[r * 64 + coff]);
      }
      #pragma unroll
      for (int m = 0; m < 4; ++m)
        #pragma unroll
        for (int n = 0; n < 4; ++n)
          acc[m][n] = __builtin_amdgcn_mfma_f32_16x16x32_bf16(af[m], bq[n], acc[m][n], 0, 0, 0);
    }
  }

  #pragma unroll
  for (int m = 0; m < 4; ++m) {
    #pragma unroll
    for (int n = 0; n < 4; ++n) {
      int col = n0 + wc * 64 + n * 16 + l15;
      float bv = BIAS ? bias[col] : 0.f;
      #pragma unroll
      for (int j = 0; j < 4; ++j) {
        int row = m0 + wr * 64 + m * 16 + l4 * 4 + j;
        float v = acc[m][n][j] + bv;
        C[(size_t)row * N + col] = (OT)v;
      }
    }
  }
}

// ---------------- fused flash attention (32x32x16, 8-wave, V-prefetch) -----
// R12 structure (best measured) + T14 V-prefetch: V's 4 global loads for
// tile kt+1 are issued at the START of tile kt's compute phase (LDS-only),
// so their HBM/L2 latency hides under ~2000cyc of MFMA/exp. They are
// consumed from registers at the next iteration's first barrier, whose
// implicit vmcnt(0) drain is then free. Costs 8 VGPRs (vv double-buffer).

__global__ __launch_bounds__(512) void attn_fused(
    const bf16* __restrict__ qkv,
    bf16* __restrict__ aout)      // [8192][1024], col = h*64+d
{
  __shared__ bf16 Ks[64 * 64];      // [key][d], source-swizzled 16B slots
  __shared__ bf16 Vt[64 * 64];      // [d][key], slot = c ^ (d&7) ^ ((d>>3)&7)
  __shared__ bf16 Pl[8][32 * 64];   // per-wave P [q][key], slot = c ^ (q&7)

  const int tid = threadIdx.x;
  const int w = tid >> 6, l = tid & 63;
  const int l31 = l & 31, hi = l >> 5;

  const int bid = blockIdx.x;            // 512 blocks
  const int c  = bid & 7, rr = bid >> 3;
  const int g  = c * 16 + (rr & 15);     // 0..127 = b*16+h
  const int qt = rr >> 4;                // 0..3
  const int h  = g & 15;
  const int b  = g >> 4;

  const bf16* base = qkv + (size_t)b * 1024 * 3072;
  const int qrow0 = qt * 256 + w * 32;

  const float qscale = 0.03125f * 1.44269504f;   // D^-0.5 * log2(e)
  bf16x8 qf[4];
  #pragma unroll
  for (int st = 0; st < 4; st++) {
    const bf16* p = base + (size_t)(qrow0 + l31) * 3072 + h * 64 + st * 16 + hi * 8;
    bf16x8 v = *reinterpret_cast<const bf16x8*>(p);
    #pragma unroll
    for (int e = 0; e < 8; e++) v[e] = (bf16)((float)v[e] * qscale);
    qf[st] = v;
  }

  bf16x8 onesf;
  #pragma unroll
  for (int e = 0; e < 8; e++) onesf[e] = (bf16)1.0f;

  f32x16 acc0 = {}, acc1 = {}, accS = {};

  const int skey  = w * 8 + (l >> 3);            // wave w stages rows w*8..w*8+7
  const int sslot = (l & 7) ^ ((l >> 3) & 7);
  // V quad staging (threads 0..255 only): keys vk0..vk0+3, d vd0..vd0+3
  const int vd0   = (tid & 15) * 4;
  const int vk0   = ((tid >> 4) & 15) * 4;
  const int vslot = (tid >> 5) & 7;              // 16B slot (key-chunk) of quad
  const int vhalf = (tid >> 4) & 1;              // 8B half
  const bf16* vbase = base + 2048 + h * 64 + vd0;

  // prefetch V quad for tile 0
  bf16x4 vv[4];
  if (tid < 256) {
    #pragma unroll
    for (int i = 0; i < 4; ++i)
      vv[i] = *reinterpret_cast<const bf16x4*>(vbase + (size_t)(vk0 + i) * 3072);
  }

  for (int kt = 0; kt < 16; ++kt) {
    __syncthreads();
    // K tile -> LDS: one gload per wave (8 waves x 8 rows = 64 rows)
    gload_lds16(base + (size_t)(kt * 64 + skey) * 3072 + 1024 + h * 64 + sslot * 8,
                (char*)Ks + w * 1024);
    // V tile: register transpose from prefetched vv -> packed b64 LDS writes
    if (tid < 256) {
      #pragma unroll
      for (int j = 0; j < 4; ++j) {
        int d = vd0 + j;
        bf16x4 o; o[0] = vv[0][j]; o[1] = vv[1][j]; o[2] = vv[2][j]; o[3] = vv[3][j];
        *reinterpret_cast<bf16x4*>(
            &Vt[d * 64 + ((vslot ^ (d & 7) ^ ((d >> 3) & 7)) * 8 + vhalf * 4)]) = o;
      }
    }
    __syncthreads();

    // issue V global loads for tile kt+1 NOW (LDS-free compute follows;
    // latency hides under it; consumed at next iteration's barrier)
    if (tid < 256 && kt < 15) {
      #pragma unroll
      for (int i = 0; i < 4; ++i)
        vv[i] = *reinterpret_cast<const bf16x4*>(
            vbase + (size_t)((kt + 1) * 64 + vk0 + i) * 3072);
    }

    #pragma unroll
    for (int ktile = 0; ktile < 2; ++ktile) {
      f32x16 s = {};
      const int key = ktile * 32 + l31;
      #pragma unroll
      for (int st = 0; st < 4; ++st) {
        const int slot = (2 * st + hi) ^ (key & 7);
        bf16x8 kf = *reinterpret_cast<const bf16x8*>(&Ks[key * 64 + slot * 8]);
        s = __builtin_amdgcn_mfma_f32_32x32x16_bf16(kf, qf[st], s, 0, 0, 0);
      }
      #pragma unroll
      for (int gq = 0; gq < 4; ++gq) {
        bf16x4 pb;
        #pragma unroll
        for (int j2 = 0; j2 < 4; ++j2) {
          float pv = __builtin_amdgcn_exp2f(s[4 * gq + j2]);
          pb[j2] = (bf16)pv;
        }
        const int chunk = ktile * 4 + gq;
        *reinterpret_cast<bf16x4*>(
            &Pl[w][l31 * 64 + ((chunk ^ (l31 & 7)) * 8 + hi * 4)]) = pb;
      }
    }

    const int d7x0 = (l31 & 7) ^ (l31 >> 3);
    const int d7x1 = d7x0 ^ 4;
    #pragma unroll
    for (int st = 0; st < 4; ++st) {
      const int cs = 2 * st + hi;
      bf16x8 pa  = *reinterpret_cast<const bf16x8*>(
          &Pl[w][l31 * 64 + ((cs ^ (l31 & 7)) * 8)]);
      accS = __builtin_amdgcn_mfma_f32_32x32x16_bf16(pa, onesf, accS, 0, 0, 0);
      bf16x8 vf0 = *reinterpret_cast<const bf16x8*>(
          &Vt[l31 * 64 + ((cs ^ d7x0) * 8)]);
      acc0 = __builtin_amdgcn_mfma_f32_32x32x16_bf16(pa, vf0, acc0, 0, 0, 0);
      bf16x8 vf1 = *reinterpret_cast<const bf16x8*>(
          &Vt[(32 + l31) * 64 + ((cs ^ d7x1) * 8)]);
      acc1 = __builtin_amdgcn_mfma_f32_32x32x16_bf16(pa, vf1, acc1, 0, 0, 0);
    }
  }

  #pragma unroll
  for (int reg = 0; reg < 16; ++reg) {
    int q_r = (reg & 3) + 8 * (reg >> 2) + 4 * hi;
    float rinv = 1.0f / accS[reg];
    size_t rowoff = ((size_t)b * 1024 + qrow0 + q_r) * 1024 + h * 64;
    aout[rowoff + l31]      = (bf16)(acc0[reg] * rinv);
    aout[rowoff + 32 + l31] = (bf16)(acc1[reg] * rinv);
  }
}

// ---------------- launch ----------------

extern "C" void kernel_launch(void* const* d_in, const int* in_sizes, int n_in,
                              void* d_out, int out_size, void* d_ws, size_t ws_size,
                              hipStream_t stream) {
  const float* x     = (const float*)d_in[0];   // [8,1024,1024]
  const float* w_in  = (const float*)d_in[1];   // [1024,3072]
  const float* w_out = (const float*)d_in[2];   // [1024,1024]
  const float* b_out = (const float*)d_in[3];   // [1024]
  float* out = (float*)d_out;                   // [8,1024,1024] fp32

  bf16* xb    = (bf16*)d_ws;                         // 8192*1024
  bf16* wint  = xb    + (size_t)8192 * 1024;         // 3072*1024  (w_in^T)
  bf16* woutt = wint  + (size_t)3072 * 1024;         // 1024*1024  (w_out^T)
  bf16* qkv   = woutt + (size_t)1024 * 1024;         // 8192*3072
  bf16* ao    = qkv   + (size_t)8192 * 3072;         // 8192*1024

  cvt_f32_to_bf16<<<8192, 256, 0, stream>>>(x, xb, 8192 * 1024);
  transpose_cvt<<<dim3(96, 32), dim3(32, 8), 0, stream>>>(w_in,  wint,  1024, 3072);
  transpose_cvt<<<dim3(32, 32), dim3(32, 8), 0, stream>>>(w_out, woutt, 1024, 1024);

  // qkv = x @ w_in   (bf16 out) - 128^2, 1536 blocks, XCD-chunked swizzle
  gemm_abt<bf16, false><<<1536, 256, 0, stream>>>(xb, wint, nullptr, qkv, 8192, 3072, 1024);

  // fused attention -> ao (bf16, [token][h*64+d]) - 8-wave blocks, 512 total
  attn_fused<<<512, 512, 0, stream>>>(qkv, ao);

  // out = ao @ w_out + b_out   (fp32 out) - 128^2, 512 blocks
  gemm_abt<float, true><<<512, 256, 0, stream>>>(ao, woutt, b_out, out, 8192, 1024, 1024);
}

// Round 16
// 156.340 us; speedup vs baseline: 1.1005x; 1.1005x over previous
//
#include <hip/hip_runtime.h>
#include <stdint.h>
#include <stddef.h>

typedef __bf16 bf16;
typedef __bf16 bf16x4 __attribute__((ext_vector_type(4)));
typedef __bf16 bf16x8 __attribute__((ext_vector_type(8)));
typedef float  f32x4  __attribute__((ext_vector_type(4)));
typedef float  f32x16 __attribute__((ext_vector_type(16)));
typedef float  f32x4v __attribute__((ext_vector_type(4)));

// async global->LDS, 16B per lane, wave-uniform LDS base + lane*16
__device__ __forceinline__ void gload_lds16(const void* g, void* lds) {
  __builtin_amdgcn_global_load_lds(
      (__attribute__((address_space(1))) void*)(uintptr_t)g,
      (__attribute__((address_space(3))) void*)lds,
      16, 0, 0);
}

// ---------------- fused input prep ----------------
// One kernel, blockIdx-range dispatch:
//  [0, 8192)        : x f32 -> bf16 (4 elem/thread)
//  [8192, 11264)    : w_in  [1024][3072] -> w_in^T  bf16 (32x32 tiles)
//  [11264, 12288)   : w_out [1024][1024] -> w_out^T bf16
// Replaces 3 serialized launches (~15us) with one 72MB stream (~11.5us floor).

__global__ __launch_bounds__(256) void prep_inputs(
    const float* __restrict__ x,     bf16* __restrict__ xb,
    const float* __restrict__ w_in,  bf16* __restrict__ wint,
    const float* __restrict__ w_out, bf16* __restrict__ woutt)
{
  __shared__ bf16 tile[32][33];
  const int bid = blockIdx.x, tid = threadIdx.x;

  if (bid < 8192) {
    int i = bid * 1024 + tid * 4;
    f32x4v v = *reinterpret_cast<const f32x4v*>(x + i);
    bf16x4 o;
    o[0] = (bf16)v[0]; o[1] = (bf16)v[1]; o[2] = (bf16)v[2]; o[3] = (bf16)v[3];
    *reinterpret_cast<bf16x4*>(xb + i) = o;
    return;
  }

  const float* in; bf16* out; int R, C, c0, r0;
  if (bid < 11264) {
    int t = bid - 8192;                 // 96 x 32 tiles
    in = w_in; out = wint; R = 1024; C = 3072;
    c0 = (t % 96) * 32; r0 = (t / 96) * 32;
  } else {
    int t = bid - 11264;                // 32 x 32 tiles
    in = w_out; out = woutt; R = 1024; C = 1024;
    c0 = (t % 32) * 32; r0 = (t / 32) * 32;
  }
  const int tx = tid & 31, ty = tid >> 5;
  #pragma unroll
  for (int i = ty; i < 32; i += 8)
    tile[i][tx] = (bf16)in[(size_t)(r0 + i) * C + (c0 + tx)];
  __syncthreads();
  #pragma unroll
  for (int i = ty; i < 32; i += 8)
    out[(size_t)(c0 + i) * R + (r0 + tx)] = tile[tx][i];
}

// ---------------- GEMM: C[M][N] = A[M][K] * Bt[N][K]^T (+bias) ----------------
// 128x128 tile, BK=64, 4 waves in 2x2, each wave 64x64 (4x4 16x16 fragments).
// Proven 2-barrier structure (67.2us GEMM1 / 786 TF, conflicts 0). Both
// 8-phase/256^2 ports (R9 drain-0, R14 counted-vmcnt) regressed to ~75us
// (1 block/CU at 128KB LDS -> whole-CU barrier stalls). Closed.
// XCD-chunked swizzle kept (bijective, grid%8==0); for GEMM2 it also aligns
// m-tiles of batch b with the XCD that attn wrote batch b's rows from.

template <typename OT, bool BIAS>
__global__ __launch_bounds__(256) void gemm_abt(
    const bf16* __restrict__ A,   // [M][K]
    const bf16* __restrict__ Bt,  // [N][K]
    const float* __restrict__ bias,
    OT* __restrict__ C, int M, int N, int K)
{
  __shared__ bf16 As[128 * 64];
  __shared__ bf16 Bs[128 * 64];

  const int tid = threadIdx.x;
  const int w = tid >> 6, l = tid & 63;
  const int l15 = l & 15, l4 = l >> 4, l7 = l & 7;
  const int wr = w >> 1, wc = w & 1;

  const int nwgx = N >> 7;
  const int nwg  = (M >> 7) * nwgx;
  const int cpx  = nwg >> 3;
  const int bid  = blockIdx.x;
  const int swz  = (bid & 7) * cpx + (bid >> 3);
  const int m0 = (swz / nwgx) * 128, n0 = (swz % nwgx) * 128;

  f32x4 acc[4][4];
  #pragma unroll
  for (int i = 0; i < 4; i++)
    #pragma unroll
    for (int j = 0; j < 4; j++) acc[i][j] = (f32x4){0.f, 0.f, 0.f, 0.f};

  const int srow  = w * 8 + (l >> 3);
  const int sslot = (l & 7) ^ ((l >> 3) & 7);
  const int KT = K >> 6;

  for (int kt = 0; kt < KT; ++kt) {
    __syncthreads();
    const int kcol = kt * 64 + sslot * 8;
    #pragma unroll
    for (int p = 0; p < 4; ++p) {
      gload_lds16(A  + (size_t)(m0 + p * 32 + srow) * K + kcol,
                  (char*)As + p * 4096 + w * 1024);
      gload_lds16(Bt + (size_t)(n0 + p * 32 + srow) * K + kcol,
                  (char*)Bs + p * 4096 + w * 1024);
    }
    __syncthreads();

    #pragma unroll
    for (int kk = 0; kk < 2; ++kk) {
      const int coff = (kk * 32 + l4 * 8) ^ (l7 << 3);
      bf16x8 af[4], bq[4];
      #pragma unroll
      for (int m = 0; m < 4; ++m) {
        int r = wr * 64 + m * 16 + l15;
        af[m] = *reinterpret_cast<const bf16x8*>(&As[r * 64 + coff]);
      }
      #pragma unroll
      for (int n = 0; n < 4; ++n) {
        int r = wc * 64 + n * 16 + l15;
        bq[n] = *reinterpret_cast<const bf16x8*>(&Bs[r * 64 + coff]);
      }
      #pragma unroll
      for (int m = 0; m < 4; ++m)
        #pragma unroll
        for (int n = 0; n < 4; ++n)
          acc[m][n] = __builtin_amdgcn_mfma_f32_16x16x32_bf16(af[m], bq[n], acc[m][n], 0, 0, 0);
    }
  }

  #pragma unroll
  for (int m = 0; m < 4; ++m) {
    #pragma unroll
    for (int n = 0; n < 4; ++n) {
      int col = n0 + wc * 64 + n * 16 + l15;
      float bv = BIAS ? bias[col] : 0.f;
      #pragma unroll
      for (int j = 0; j < 4; ++j) {
        int row = m0 + wr * 64 + m * 16 + l4 * 4 + j;
        float v = acc[m][n][j] + bv;
        C[(size_t)row * N + col] = (OT)v;
      }
    }
  }
}

// ---------------- fused flash attention (32x32x16, 8-wave shared K/V) ------
// EXACT R12 structure (best measured, 159.8us total; VGPR 80 = 3 blocks/CU).
// R15's V-prefetch regressed ~13us: vv held across compute pushed VGPR past
// the 85 cliff (3->2 blocks/CU). Pipelining attempts on this kernel: 4/4
// negative (dbuf R7, in-reg P R6, setprio R10, V-prefetch R15) - attn is
// occupancy-bound; keep registers lean.

__global__ __launch_bounds__(512) void attn_fused(
    const bf16* __restrict__ qkv,
    bf16* __restrict__ aout)      // [8192][1024], col = h*64+d
{
  __shared__ bf16 Ks[64 * 64];      // [key][d], source-swizzled 16B slots
  __shared__ bf16 Vt[64 * 64];      // [d][key], slot = c ^ (d&7) ^ ((d>>3)&7)
  __shared__ bf16 Pl[8][32 * 64];   // per-wave P [q][key], slot = c ^ (q&7)

  const int tid = threadIdx.x;
  const int w = tid >> 6, l = tid & 63;
  const int l31 = l & 31, hi = l >> 5;

  // XCD-grouped swizzle: batch b lands entirely on XCD b (K/V L2 reuse;
  // also aligns ao rows with GEMM2's m-tiles on the same XCD).
  const int bid = blockIdx.x;            // 512 blocks
  const int c  = bid & 7, rr = bid >> 3;
  const int g  = c * 16 + (rr & 15);     // 0..127 = b*16+h
  const int qt = rr >> 4;                // 0..3
  const int h  = g & 15;
  const int b  = g >> 4;

  const bf16* base = qkv + (size_t)b * 1024 * 3072;
  const int qrow0 = qt * 256 + w * 32;

  const float qscale = 0.03125f * 1.44269504f;   // D^-0.5 * log2(e)
  bf16x8 qf[4];
  #pragma unroll
  for (int st = 0; st < 4; st++) {
    const bf16* p = base + (size_t)(qrow0 + l31) * 3072 + h * 64 + st * 16 + hi * 8;
    bf16x8 v = *reinterpret_cast<const bf16x8*>(p);
    #pragma unroll
    for (int e = 0; e < 8; e++) v[e] = (bf16)((float)v[e] * qscale);
    qf[st] = v;
  }

  bf16x8 onesf;
  #pragma unroll
  for (int e = 0; e < 8; e++) onesf[e] = (bf16)1.0f;

  f32x16 acc0 = {}, acc1 = {}, accS = {};

  const int skey  = w * 8 + (l >> 3);            // wave w stages rows w*8..w*8+7
  const int sslot = (l & 7) ^ ((l >> 3) & 7);
  const int vd0   = (tid & 15) * 4;
  const int vk0   = ((tid >> 4) & 15) * 4;
  const int vslot = (tid >> 5) & 7;
  const int vhalf = (tid >> 4) & 1;

  for (int kt = 0; kt < 16; ++kt) {
    __syncthreads();
    gload_lds16(base + (size_t)(kt * 64 + skey) * 3072 + 1024 + h * 64 + sslot * 8,
                (char*)Ks + w * 1024);
    if (tid < 256) {
      bf16x4 vv[4];
      #pragma unroll
      for (int i = 0; i < 4; ++i)
        vv[i] = *reinterpret_cast<const bf16x4*>(
            base + (size_t)(kt * 64 + vk0 + i) * 3072 + 2048 + h * 64 + vd0);
      #pragma unroll
      for (int j = 0; j < 4; ++j) {
        int d = vd0 + j;
        bf16x4 o; o[0] = vv[0][j]; o[1] = vv[1][j]; o[2] = vv[2][j]; o[3] = vv[3][j];
        *reinterpret_cast<bf16x4*>(
            &Vt[d * 64 + ((vslot ^ (d & 7) ^ ((d >> 3) & 7)) * 8 + vhalf * 4)]) = o;
      }
    }
    __syncthreads();

    #pragma unroll
    for (int ktile = 0; ktile < 2; ++ktile) {
      f32x16 s = {};
      const int key = ktile * 32 + l31;
      #pragma unroll
      for (int st = 0; st < 4; ++st) {
        const int slot = (2 * st + hi) ^ (key & 7);
        bf16x8 kf = *reinterpret_cast<const bf16x8*>(&Ks[key * 64 + slot * 8]);
        s = __builtin_amdgcn_mfma_f32_32x32x16_bf16(kf, qf[st], s, 0, 0, 0);
      }
      #pragma unroll
      for (int gq = 0; gq < 4; ++gq) {
        bf16x4 pb;
        #pragma unroll
        for (int j2 = 0; j2 < 4; ++j2) {
          float pv = __builtin_amdgcn_exp2f(s[4 * gq + j2]);
          pb[j2] = (bf16)pv;
        }
        const int chunk = ktile * 4 + gq;
        *reinterpret_cast<bf16x4*>(
            &Pl[w][l31 * 64 + ((chunk ^ (l31 & 7)) * 8 + hi * 4)]) = pb;
      }
    }

    const int d7x0 = (l31 & 7) ^ (l31 >> 3);
    const int d7x1 = d7x0 ^ 4;
    #pragma unroll
    for (int st = 0; st < 4; ++st) {
      const int cs = 2 * st + hi;
      bf16x8 pa  = *reinterpret_cast<const bf16x8*>(
          &Pl[w][l31 * 64 + ((cs ^ (l31 & 7)) * 8)]);
      accS = __builtin_amdgcn_mfma_f32_32x32x16_bf16(pa, onesf, accS, 0, 0, 0);
      bf16x8 vf0 = *reinterpret_cast<const bf16x8*>(
          &Vt[l31 * 64 + ((cs ^ d7x0) * 8)]);
      acc0 = __builtin_amdgcn_mfma_f32_32x32x16_bf16(pa, vf0, acc0, 0, 0, 0);
      bf16x8 vf1 = *reinterpret_cast<const bf16x8*>(
          &Vt[(32 + l31) * 64 + ((cs ^ d7x1) * 8)]);
      acc1 = __builtin_amdgcn_mfma_f32_32x32x16_bf16(pa, vf1, acc1, 0, 0, 0);
    }
  }

  #pragma unroll
  for (int reg = 0; reg < 16; ++reg) {
    int q_r = (reg & 3) + 8 * (reg >> 2) + 4 * hi;
    float rinv = 1.0f / accS[reg];
    size_t rowoff = ((size_t)b * 1024 + qrow0 + q_r) * 1024 + h * 64;
    aout[rowoff + l31]      = (bf16)(acc0[reg] * rinv);
    aout[rowoff + 32 + l31] = (bf16)(acc1[reg] * rinv);
  }
}

// ---------------- launch ----------------

extern "C" void kernel_launch(void* const* d_in, const int* in_sizes, int n_in,
                              void* d_out, int out_size, void* d_ws, size_t ws_size,
                              hipStream_t stream) {
  const float* x     = (const float*)d_in[0];   // [8,1024,1024]
  const float* w_in  = (const float*)d_in[1];   // [1024,3072]
  const float* w_out = (const float*)d_in[2];   // [1024,1024]
  const float* b_out = (const float*)d_in[3];   // [1024]
  float* out = (float*)d_out;                   // [8,1024,1024] fp32

  bf16* xb    = (bf16*)d_ws;                         // 8192*1024
  bf16* wint  = xb    + (size_t)8192 * 1024;         // 3072*1024  (w_in^T)
  bf16* woutt = wint  + (size_t)3072 * 1024;         // 1024*1024  (w_out^T)
  bf16* qkv   = woutt + (size_t)1024 * 1024;         // 8192*3072
  bf16* ao    = qkv   + (size_t)8192 * 3072;         // 8192*1024

  // fused input prep: x->bf16 + w_in^T + w_out^T in one launch
  prep_inputs<<<12288, 256, 0, stream>>>(x, xb, w_in, wint, w_out, woutt);

  // qkv = x @ w_in   (bf16 out) - 128^2, 1536 blocks, XCD-chunked swizzle
  gemm_abt<bf16, false><<<1536, 256, 0, stream>>>(xb, wint, nullptr, qkv, 8192, 3072, 1024);

  // fused attention -> ao (bf16, [token][h*64+d]) - 8-wave blocks, 512 total
  attn_fused<<<512, 512, 0, stream>>>(qkv, ao);

  // out = ao @ w_out + b_out   (fp32 out) - 128^2, 512 blocks
  gemm_abt<float, true><<<512, 256, 0, stream>>>(ao, woutt, b_out, out, 8192, 1024, 1024);
}